// Round 4
// baseline (174.276 us; speedup 1.0000x reference)
//
#include <hip/hip_runtime.h>
#include <hip/hip_bf16.h>
#include <cstdint>

#define BB 64
#define NN 512
#define MM 1024
#define DD 128

typedef __bf16 bf16x8 __attribute__((ext_vector_type(8)));
typedef float f32x4 __attribute__((ext_vector_type(4)));

static __device__ __forceinline__ unsigned short f2bf(float f) {
    union { float f; unsigned int i; } v; v.f = f;
    unsigned int x = v.i;
    x += 0x7FFFu + ((x >> 16) & 1u);   // RNE
    return (unsigned short)(x >> 16);
}
// packed v_cvt_pk_bf16_f32: low = a, high = b
static __device__ __forceinline__ unsigned int f2bf2(float a, float b) {
    union { __hip_bfloat162 h; unsigned int u; } c;
    c.h = __float22bfloat162_rn(make_float2(a, b));
    return c.u;
}
// async global->LDS DMA, 16 B per lane, dest = wave-uniform base + lane*16
static __device__ __forceinline__ void async16(const void* g, void* l) {
    __builtin_amdgcn_global_load_lds(
        (const __attribute__((address_space(1))) void*)g,
        (__attribute__((address_space(3))) void*)l, 16, 0, 0);
}

// ---------- Kernel 0: W fp32 -> bf16, XOR-swizzled rows, Wu pre-scaled -------
// out[0,16384): Wu * log2(e), swizzled; out[16384,32768): Wv, swizzled.
// Swizzle: element (r,c) stored at r*128 + ((c>>3 ^ (r&7))<<3) + (c&7), so a
// linear global_load_lds copy yields conflict-free XOR-swizzled LDS reads.
__global__ __launch_bounds__(256) void wcvt_kernel(
    const float* __restrict__ Wu, const float* __restrict__ Wv,
    unsigned short* __restrict__ out)
{
    const float* W = blockIdx.x ? Wv : Wu;
    unsigned short* o = out + blockIdx.x * 16384;
    const float s = blockIdx.x ? 1.0f : 1.44269504088896f;   // log2(e) for Wu
    #pragma unroll
    for (int i = 0; i < 8; ++i) {
        int ch = i * 256 + threadIdx.x;         // 2048 chunks of 8 elems
        int r = ch >> 4, c = ch & 15;
        const float4* src = (const float4*)(W + r * 128 + c * 8);
        float4 a = src[0], b = src[1];
        uint4 v = { f2bf2(a.x * s, a.y * s), f2bf2(a.z * s, a.w * s),
                    f2bf2(b.x * s, b.y * s), f2bf2(b.z * s, b.w * s) };
        *(uint4*)&o[r * 128 + ((c ^ (r & 7)) << 3)] = v;
    }
}

// ---------- Kernel 1: Vp = relu(h_p @ Wv^T + b) ------------------------------
// W arrives bf16 pre-swizzled: DMA'd straight to LDS, read with XOR.
// Outputs: Vp row-major tiles [b][mt][64][128], VpT tiled [b][mt][128][64].
__global__ __launch_bounds__(256, 4) void proj_v_kernel(
    const float* __restrict__ X,
    const unsigned short* __restrict__ Wvb,   // (128,128) bf16 swizzled
    const float* __restrict__ bias,
    unsigned short* __restrict__ Y,
    unsigned short* __restrict__ YT)
{
    __shared__ __align__(16) unsigned short Ws[17408];   // 34816 B (W | Ys+Ts)
    unsigned short* Ys = Ws;            // 64*128 shorts
    unsigned short* Ts = Ws + 8192;     // 128*72 shorts
    const int t = threadIdx.x;
    const int lane = t & 63;
    const int wave = t >> 6;
    const int n16 = lane & 15, q = lane >> 4;
    const long row0 = (long)blockIdx.x * 64;

    // X loads FIRST (latency overlaps W DMA below)
    float4 xv[8];
    {
        const float* xrow = X + (row0 + wave * 16 + n16) * DD + q * 8;
        #pragma unroll
        for (int kk = 0; kk < 4; ++kk) {
            xv[2 * kk]     = *(const float4*)(xrow + kk * 32);
            xv[2 * kk + 1] = *(const float4*)(xrow + kk * 32 + 4);
        }
    }
    // DMA pre-swizzled bf16 W into LDS (no cvt, no fp32 traffic)
    #pragma unroll
    for (int i = 0; i < 8; ++i)
        async16(Wvb + (wave * 512 + i * 64 + lane) * 8, Ws + wave * 4096 + i * 512);
    __syncthreads();

    f32x4 acc[8];
    #pragma unroll
    for (int j = 0; j < 8; ++j) acc[j] = {0.f, 0.f, 0.f, 0.f};

    #pragma unroll
    for (int kk = 0; kk < 4; ++kk) {
        float4 x0 = xv[2 * kk], x1 = xv[2 * kk + 1];
        union { bf16x8 v; unsigned int u[4]; } a;
        a.u[0] = f2bf2(x0.x, x0.y); a.u[1] = f2bf2(x0.z, x0.w);
        a.u[2] = f2bf2(x1.x, x1.y); a.u[3] = f2bf2(x1.z, x1.w);
        #pragma unroll
        for (int j = 0; j < 8; ++j) {
            bf16x8 b = *(const bf16x8*)&Ws[(j * 16 + n16) * 128
                                           + (((q + 4 * kk) ^ (n16 & 7)) << 3)];
            acc[j] = __builtin_amdgcn_mfma_f32_16x16x32_bf16(a.v, b, acc[j], 0, 0, 0);
        }
    }

    unsigned short yb[8][4];
    #pragma unroll
    for (int j = 0; j < 8; ++j) {
        const float bv = bias[j * 16 + n16];
        float y[4];
        #pragma unroll
        for (int r = 0; r < 4; ++r) {
            float v = acc[j][r] + bv;
            y[r] = v > 0.f ? v : 0.f;
        }
        uint2 u = { f2bf2(y[0], y[1]), f2bf2(y[2], y[3]) };
        *(uint2*)&yb[j][0] = u;
    }
    __syncthreads();   // Ws reads done; reuse as Ys/Ts

    #pragma unroll
    for (int j = 0; j < 8; ++j) {
        const int e = j * 16 + n16;
        #pragma unroll
        for (int r = 0; r < 4; ++r)
            Ys[(wave * 16 + q * 4 + r) * 128 + e] = yb[j][r];
        *(uint2*)&Ts[e * 72 + wave * 16 + q * 4] = *(uint2*)&yb[j][0];
    }
    __syncthreads();

    {
        uint4* dstY = (uint4*)(Y + row0 * DD);
        const long b = row0 >> 10;
        const long mt = (row0 & 1023) >> 6;
        uint4* dstT = (uint4*)(YT + ((b * 16 + mt) * 128) * 64);
        #pragma unroll
        for (int i = 0; i < 4; ++i) {
            int idx = i * 256 + t;
            dstY[idx] = ((const uint4*)Ys)[idx];
            int e = idx >> 3, m = (idx & 7) * 8;
            dstT[idx] = *(const uint4*)&Ts[e * 72 + m];
        }
    }
}

// ---------- Kernel 2: fused proj_c + bilinear attention ----------------------
// LDS (shorts): [0,8192) buf0 | Ws lo   [8192,16384) buf1 | Ws hi
//               [16384,24576) Ucs (phase-1) | Ps[16384,20992) (main loop)
// Total 49152 B -> 3 blocks/CU (was 58368 -> 2).  __launch_bounds__(256,3).
// Phase 1: Wu bf16 pre-swizzled+pre-scaled by log2(e), DMA'd to LDS; Uc stored
// swizzled in Ucs; all 64 Uc rows hoisted to Bg regs; ucred (scaled) in regs.
// Main loop per mt (2 VpT buffers, DMA issued at iteration TOP = ~full iter of
// latency cover): DMA(mt+1)->buf[(mt+1)&1]; A-prefetch(mt+1)->regs; QK from
// regs; exp2 -> Ps; barrier1 lgkm-only (DMA crosses); PV from buf[mt&1];
// barrier2 vmcnt(4) (drains DMA(mt+1), keeps 4 A-prefetches in flight; the
// sched_barrier after the DMA cluster pins DMA-older-than-Apf issue order).
static __device__ __forceinline__ void bar_lgkm() {
    asm volatile("s_waitcnt lgkmcnt(0)" ::: "memory");
    __builtin_amdgcn_s_barrier();
    __builtin_amdgcn_sched_barrier(0);
}

static __device__ __forceinline__ void attn_iter(
    int mt, unsigned short* smem, unsigned short* Ps,
    const unsigned short* __restrict__ vpb,
    const unsigned short* __restrict__ vtb,
    int wave, int lane, int n16, int q, int a_off,
    const bf16x8 (&Bg)[4][4],
    bf16x8 (&aC)[4], bf16x8 (&aN)[4],
    f32x4 (&O)[8], float (&lpart)[4])
{
    const int nx = (mt + 1 > 15) ? 15 : mt + 1;   // clamp keeps vmcnt uniform
    // DMA VpT tile mt+1 into buf[(mt+1)&1] (read next iteration)
    {
        const unsigned short* st = vtb + nx * 8192;
        unsigned short* dst = smem + ((mt + 1) & 1) * 8192 + wave * 2048;
        #pragma unroll
        for (int i = 0; i < 4; ++i) {
            int L = wave * 256 + i * 64 + lane;
            int r = L >> 3, sc = L & 7, c = sc ^ (r & 7);
            async16(st + r * 64 + c * 8, dst + i * 512);
        }
    }
    __builtin_amdgcn_sched_barrier(0);   // DMA issues before Apf (vmcnt order)
    // A-frag prefetch for tile mt+1 (global->reg, consumed next iteration)
    {
        const unsigned short* pa = vpb + nx * 8192 + a_off;
        #pragma unroll
        for (int kk = 0; kk < 4; ++kk)
            aN[kk] = *(const bf16x8*)(pa + kk * 32);
    }

    // QK (m-split): S^T rows m = wave*16+q*4+r, cols n = j*16+n16. Pure regs.
    f32x4 S[4];
    #pragma unroll
    for (int j = 0; j < 4; ++j) S[j] = {0.f, 0.f, 0.f, 0.f};
    __builtin_amdgcn_s_setprio(1);
    #pragma unroll
    for (int kk = 0; kk < 4; ++kk) {
        #pragma unroll
        for (int j = 0; j < 4; ++j)
            S[j] = __builtin_amdgcn_mfma_f32_16x16x32_bf16(aC[kk], Bg[j][kk], S[j], 0, 0, 0);
    }
    __builtin_amdgcn_s_setprio(0);

    // p = exp2(S) (Uc pre-scaled); write P[n][m] slices to shared Ps
    #pragma unroll
    for (int j = 0; j < 4; ++j) {
        float p0 = __builtin_exp2f(S[j][0]);
        float p1 = __builtin_exp2f(S[j][1]);
        float p2 = __builtin_exp2f(S[j][2]);
        float p3 = __builtin_exp2f(S[j][3]);
        lpart[j] += (p0 + p1) + (p2 + p3);
        uint2 u = { f2bf2(p0, p1), f2bf2(p2, p3) };
        *(uint2*)&Ps[(j * 16 + n16) * 72 + wave * 16 + q * 4] = u;
    }
    bar_lgkm();   // barrier 1: P complete; DMA + prefetch stay in flight

    // PV (n-split): O[n][d] for this wave's 16 n-rows; VTs = buf[mt&1]
    const unsigned short* VTs = smem + (mt & 1) * 8192;
    __builtin_amdgcn_s_setprio(1);
    #pragma unroll
    for (int kk = 0; kk < 2; ++kk) {
        bf16x8 a = *(const bf16x8*)&Ps[(wave * 16 + n16) * 72 + kk * 32 + q * 8];
        #pragma unroll
        for (int j = 0; j < 8; ++j) {
            bf16x8 bb = *(const bf16x8*)&VTs[(j * 16 + n16) * 64 + ((kk * 4 + q) ^ (n16 & 7)) * 8];
            O[j] = __builtin_amdgcn_mfma_f32_16x16x32_bf16(a, bb, O[j], 0, 0, 0);
        }
    }
    __builtin_amdgcn_s_setprio(0);
    // barrier 2: Ps/VTs reads done; DMA(mt+1) drained; Apf(mt+1) in flight
    asm volatile("s_waitcnt vmcnt(4) lgkmcnt(0)" ::: "memory");
    __builtin_amdgcn_s_barrier();
    __builtin_amdgcn_sched_barrier(0);
}

__global__ __launch_bounds__(256, 3) void attn_kernel(
    const float* __restrict__ hc,             // (B*512,128) fp32
    const unsigned short* __restrict__ Wub,   // (128,128) bf16 swz, pre-scaled
    const float* __restrict__ Ub,             // (128) fp32
    const unsigned short* __restrict__ Vp,    // (B,16,64,128) bf16 tiled
    const unsigned short* __restrict__ VpT,   // (B,16,128,64) bf16 tiled
    float* __restrict__ part)                 // (B*8,128) fp32
{
    __shared__ __align__(16) unsigned short smem[24576];   // 49152 B
    unsigned short* Ws  = smem;            // phase-1: 16384 shorts
    unsigned short* Ucs = smem + 16384;    // phase-1: 8192 shorts (swizzled)
    unsigned short* Ps  = smem + 16384;    // main loop: 4608 shorts

    const int t = threadIdx.x;
    const int lane = t & 63;
    const int wave = t >> 6;
    const int n16 = lane & 15, q = lane >> 4;

    const int id = blockIdx.x;
    const int xcd = id & 7;
    const int slot = id >> 3;
    const int b = xcd * 8 + (slot >> 3);
    const int nt = slot & 7;

    const unsigned short* vpb = Vp + (long)b * MM * DD;    // 16 tiles of 8192
    const unsigned short* vtb = VpT + (long)b * MM * DD;

    const float LOG2E = 1.44269504088896f;
    const float RLN2  = 0.69314718055994531f;   // 1/log2(e)

    // ---- Phase 1: Uc (pre-scaled by log2e via W) for this block's 64 rows ----
    float4 xv[8];
    {
        const float* xrow = hc + ((long)b * NN + nt * 64 + wave * 16 + n16) * DD + q * 8;
        #pragma unroll
        for (int kk = 0; kk < 4; ++kk) {
            xv[2 * kk]     = *(const float4*)(xrow + kk * 32);
            xv[2 * kk + 1] = *(const float4*)(xrow + kk * 32 + 4);
        }
    }
    #pragma unroll
    for (int i = 0; i < 8; ++i)
        async16(Wub + (wave * 512 + i * 64 + lane) * 8, Ws + wave * 4096 + i * 512);
    __syncthreads();

    f32x4 acc[8];
    #pragma unroll
    for (int j = 0; j < 8; ++j) acc[j] = {0.f, 0.f, 0.f, 0.f};
    #pragma unroll
    for (int kk = 0; kk < 4; ++kk) {
        float4 x0 = xv[2 * kk], x1 = xv[2 * kk + 1];
        union { bf16x8 v; unsigned int u[4]; } a;
        a.u[0] = f2bf2(x0.x, x0.y); a.u[1] = f2bf2(x0.z, x0.w);
        a.u[2] = f2bf2(x1.x, x1.y); a.u[3] = f2bf2(x1.z, x1.w);
        #pragma unroll
        for (int j = 0; j < 8; ++j) {
            bf16x8 bb = *(const bf16x8*)&Ws[(j * 16 + n16) * 128
                                            + (((q + 4 * kk) ^ (n16 & 7)) << 3)];
            acc[j] = __builtin_amdgcn_mfma_f32_16x16x32_bf16(a.v, bb, acc[j], 0, 0, 0);
        }
    }
    float ucred[8];
    #pragma unroll
    for (int j = 0; j < 8; ++j) {
        const float bv = Ub[j * 16 + n16] * LOG2E;   // match pre-scaled W
        float s = 0.f;
        #pragma unroll
        for (int r = 0; r < 4; ++r) {
            float v = acc[j][r] + bv;
            v = v > 0.f ? v : 0.f;
            s += v;                                   // scaled; x RLN2 at end
            int row = wave * 16 + q * 4 + r;
            int pc = (2 * j + (n16 >> 3)) ^ (row & 7);
            Ucs[row * 128 + pc * 8 + (n16 & 7)] = f2bf(v);
        }
        ucred[j] = s;
    }
    __syncthreads();                          // (A): Ucs ready, Ws dead

    // ALL 64 n-rows of Uc as B-frags in registers (16 frags = 64 VGPRs)
    bf16x8 Bg[4][4];
    #pragma unroll
    for (int j = 0; j < 4; ++j)
        #pragma unroll
        for (int kk = 0; kk < 4; ++kk)
            Bg[j][kk] = *(const bf16x8*)&Ucs[(j * 16 + n16) * 128
                                             + (((q + 4 * kk) ^ (n16 & 7)) << 3)];

    // Prologue: A-frags tile 0 + DMA VpT tile 0 into buf0 (Ws dead)
    const int a_off = (wave * 16 + n16) * 128 + q * 8;
    bf16x8 aA[4], aB[4];
    #pragma unroll
    for (int kk = 0; kk < 4; ++kk)
        aA[kk] = *(const bf16x8*)&vpb[a_off + kk * 32];
    {
        unsigned short* dst = smem + wave * 2048;
        #pragma unroll
        for (int i = 0; i < 4; ++i) {
            int L = wave * 256 + i * 64 + lane;
            int r = L >> 3, sc = L & 7, c = sc ^ (r & 7);
            async16(vtb + r * 64 + c * 8, dst + i * 512);
        }
    }
    asm volatile("s_waitcnt vmcnt(0) lgkmcnt(0)" ::: "memory");
    __builtin_amdgcn_s_barrier();
    __builtin_amdgcn_sched_barrier(0);

    // ---- Main loop ----
    f32x4 O[8];
    #pragma unroll
    for (int j = 0; j < 8; ++j) O[j] = {0.f, 0.f, 0.f, 0.f};
    float lpart[4] = {0.f, 0.f, 0.f, 0.f};

    #pragma unroll 1
    for (int mt = 0; mt < 16; mt += 2) {
        attn_iter(mt,     smem, Ps, vpb, vtb, wave, lane, n16, q, a_off, Bg, aA, aB, O, lpart);
        attn_iter(mt + 1, smem, Ps, vpb, vtb, wave, lane, n16, q, a_off, Bg, aB, aA, O, lpart);
    }

    // ---- l reduction: lpart[j] covers n = j*16+n16 over this wave's m & q ----
    #pragma unroll
    for (int j = 0; j < 4; ++j) {
        lpart[j] += __shfl_xor(lpart[j], 16);
        lpart[j] += __shfl_xor(lpart[j], 32);
    }
    float* lred = (float*)Ps;               // 256 floats
    float* red  = (float*)Ps + 256;         // 512 floats
    if (q == 0) {
        #pragma unroll
        for (int j = 0; j < 4; ++j)
            lred[wave * 64 + j * 16 + n16] = lpart[j];
    }
    __syncthreads();

    float inv[4];
    #pragma unroll
    for (int r = 0; r < 4; ++r) {
        int n = wave * 16 + q * 4 + r;
        inv[r] = 1.0f / (lred[n] + lred[64 + n] + lred[128 + n] + lred[192 + n]);
    }

    // per-wave partial over its 16 n-rows, then cross-wave reduction
    #pragma unroll
    for (int j = 0; j < 8; ++j) {
        float s = ucred[j] * RLN2
                + O[j][0] * inv[0] + O[j][1] * inv[1]
                + O[j][2] * inv[2] + O[j][3] * inv[3];
        s += __shfl_xor(s, 16);
        s += __shfl_xor(s, 32);
        if (q == 0)
            red[wave * 128 + j * 16 + n16] = s;
    }
    __syncthreads();
    if (t < 128) {
        float tot = red[t] + red[128 + t] + red[256 + t] + red[384 + t];
        part[(long)(b * 8 + nt) * DD + t] = tot;
    }
}

// ---------- Kernel 3: out[b][d] = (Sigma_nt part) * q[d] / N -----------------
__global__ __launch_bounds__(256) void finalize_kernel(
    const float* __restrict__ part, const float* __restrict__ qv,
    float* __restrict__ out)
{
    int i = blockIdx.x * 256 + threadIdx.x;     // 8192
    int b = i >> 7, d = i & 127;
    const float* p = part + (long)b * 8 * DD + d;
    float s = 0.f;
    #pragma unroll
    for (int nt = 0; nt < 8; ++nt) s += p[nt * DD];
    out[i] = s * qv[d] * (1.0f / (float)NN);
}

extern "C" void kernel_launch(void* const* d_in, const int* in_sizes, int n_in,
                              void* d_out, int out_size, void* d_ws, size_t ws_size,
                              hipStream_t stream) {
    const float* h_c = (const float*)d_in[0];
    const float* h_p = (const float*)d_in[1];
    const float* U_w = (const float*)d_in[2];
    const float* U_b = (const float*)d_in[3];
    const float* V_w = (const float*)d_in[4];
    const float* V_b = (const float*)d_in[5];
    const float* qv  = (const float*)d_in[6];
    float* out = (float*)d_out;

    unsigned short* Vp  = (unsigned short*)d_ws;                 // (B,16,64,128) bf16
    unsigned short* VpT = Vp + (size_t)BB * MM * DD;             // (B,16,128,64) bf16
    float* part = (float*)(VpT + (size_t)BB * MM * DD);          // (B*8,128) fp32
    unsigned short* Wcv = (unsigned short*)(part + (size_t)BB * 8 * DD); // 2x 16384

    wcvt_kernel<<<2, 256, 0, stream>>>(U_w, V_w, Wcv);
    proj_v_kernel<<<BB * MM / 64, 256, 0, stream>>>(h_p, Wcv + 16384, V_b, Vp, VpT);
    attn_kernel<<<512, 256, 0, stream>>>(h_c, Wcv, U_b, Vp, VpT, part);
    finalize_kernel<<<32, 256, 0, stream>>>(part, qv, out);
}

// Round 5
// 136.142 us; speedup vs baseline: 1.2801x; 1.2801x over previous
//
#include <hip/hip_runtime.h>
#include <hip/hip_bf16.h>
#include <cstdint>

#define BB 64
#define NN 512
#define MM 1024
#define DD 128

typedef __bf16 bf16x8 __attribute__((ext_vector_type(8)));
typedef float f32x4 __attribute__((ext_vector_type(4)));

static __device__ __forceinline__ unsigned short f2bf(float f) {
    union { float f; unsigned int i; } v; v.f = f;
    unsigned int x = v.i;
    x += 0x7FFFu + ((x >> 16) & 1u);   // RNE
    return (unsigned short)(x >> 16);
}
// packed v_cvt_pk_bf16_f32: low = a, high = b
static __device__ __forceinline__ unsigned int f2bf2(float a, float b) {
    union { __hip_bfloat162 h; unsigned int u; } c;
    c.h = __float22bfloat162_rn(make_float2(a, b));
    return c.u;
}
// async global->LDS DMA, 16 B per lane, dest = wave-uniform base + lane*16
static __device__ __forceinline__ void async16(const void* g, void* l) {
    __builtin_amdgcn_global_load_lds(
        (const __attribute__((address_space(1))) void*)g,
        (__attribute__((address_space(3))) void*)l, 16, 0, 0);
}

// ---------- Kernel 0: W fp32 -> bf16, XOR-swizzled rows, Wu pre-scaled -------
// out[0,16384): Wu * log2(e), swizzled; out[16384,32768): Wv, swizzled.
// Swizzle: element (r,c) stored at r*128 + ((c>>3 ^ (r&7))<<3) + (c&7), so a
// linear global_load_lds copy yields conflict-free XOR-swizzled LDS reads.
__global__ __launch_bounds__(256) void wcvt_kernel(
    const float* __restrict__ Wu, const float* __restrict__ Wv,
    unsigned short* __restrict__ out)
{
    const float* W = blockIdx.x ? Wv : Wu;
    unsigned short* o = out + blockIdx.x * 16384;
    const float s = blockIdx.x ? 1.0f : 1.44269504088896f;   // log2(e) for Wu
    #pragma unroll
    for (int i = 0; i < 8; ++i) {
        int ch = i * 256 + threadIdx.x;         // 2048 chunks of 8 elems
        int r = ch >> 4, c = ch & 15;
        const float4* src = (const float4*)(W + r * 128 + c * 8);
        float4 a = src[0], b = src[1];
        uint4 v = { f2bf2(a.x * s, a.y * s), f2bf2(a.z * s, a.w * s),
                    f2bf2(b.x * s, b.y * s), f2bf2(b.z * s, b.w * s) };
        *(uint4*)&o[r * 128 + ((c ^ (r & 7)) << 3)] = v;
    }
}

// ---------- Kernel 1: Vp = relu(h_p @ Wv^T + b) ------------------------------
// W arrives bf16 pre-swizzled: DMA'd straight to LDS, read with XOR.
// Outputs: Vp row-major tiles [b][mt][64][128], VpT tiled [b][mt][128][64].
__global__ __launch_bounds__(256, 4) void proj_v_kernel(
    const float* __restrict__ X,
    const unsigned short* __restrict__ Wvb,   // (128,128) bf16 swizzled
    const float* __restrict__ bias,
    unsigned short* __restrict__ Y,
    unsigned short* __restrict__ YT)
{
    __shared__ __align__(16) unsigned short Ws[17408];   // 34816 B (W | Ys+Ts)
    unsigned short* Ys = Ws;            // 64*128 shorts
    unsigned short* Ts = Ws + 8192;     // 128*72 shorts
    const int t = threadIdx.x;
    const int lane = t & 63;
    const int wave = t >> 6;
    const int n16 = lane & 15, q = lane >> 4;
    const long row0 = (long)blockIdx.x * 64;

    // X loads FIRST (latency overlaps W DMA below)
    float4 xv[8];
    {
        const float* xrow = X + (row0 + wave * 16 + n16) * DD + q * 8;
        #pragma unroll
        for (int kk = 0; kk < 4; ++kk) {
            xv[2 * kk]     = *(const float4*)(xrow + kk * 32);
            xv[2 * kk + 1] = *(const float4*)(xrow + kk * 32 + 4);
        }
    }
    // DMA pre-swizzled bf16 W into LDS (no cvt, no fp32 traffic)
    #pragma unroll
    for (int i = 0; i < 8; ++i)
        async16(Wvb + (wave * 512 + i * 64 + lane) * 8, Ws + wave * 4096 + i * 512);
    __syncthreads();

    f32x4 acc[8];
    #pragma unroll
    for (int j = 0; j < 8; ++j) acc[j] = {0.f, 0.f, 0.f, 0.f};

    #pragma unroll
    for (int kk = 0; kk < 4; ++kk) {
        float4 x0 = xv[2 * kk], x1 = xv[2 * kk + 1];
        union { bf16x8 v; unsigned int u[4]; } a;
        a.u[0] = f2bf2(x0.x, x0.y); a.u[1] = f2bf2(x0.z, x0.w);
        a.u[2] = f2bf2(x1.x, x1.y); a.u[3] = f2bf2(x1.z, x1.w);
        #pragma unroll
        for (int j = 0; j < 8; ++j) {
            bf16x8 b = *(const bf16x8*)&Ws[(j * 16 + n16) * 128
                                           + (((q + 4 * kk) ^ (n16 & 7)) << 3)];
            acc[j] = __builtin_amdgcn_mfma_f32_16x16x32_bf16(a.v, b, acc[j], 0, 0, 0);
        }
    }

    unsigned short yb[8][4];
    #pragma unroll
    for (int j = 0; j < 8; ++j) {
        const float bv = bias[j * 16 + n16];
        float y[4];
        #pragma unroll
        for (int r = 0; r < 4; ++r) {
            float v = acc[j][r] + bv;
            y[r] = v > 0.f ? v : 0.f;
        }
        uint2 u = { f2bf2(y[0], y[1]), f2bf2(y[2], y[3]) };
        *(uint2*)&yb[j][0] = u;
    }
    __syncthreads();   // Ws reads done; reuse as Ys/Ts

    #pragma unroll
    for (int j = 0; j < 8; ++j) {
        const int e = j * 16 + n16;
        #pragma unroll
        for (int r = 0; r < 4; ++r)
            Ys[(wave * 16 + q * 4 + r) * 128 + e] = yb[j][r];
        *(uint2*)&Ts[e * 72 + wave * 16 + q * 4] = *(uint2*)&yb[j][0];
    }
    __syncthreads();

    {
        uint4* dstY = (uint4*)(Y + row0 * DD);
        const long b = row0 >> 10;
        const long mt = (row0 & 1023) >> 6;
        uint4* dstT = (uint4*)(YT + ((b * 16 + mt) * 128) * 64);
        #pragma unroll
        for (int i = 0; i < 4; ++i) {
            int idx = i * 256 + t;
            dstY[idx] = ((const uint4*)Ys)[idx];
            int e = idx >> 3, m = (idx & 7) * 8;
            dstT[idx] = *(const uint4*)&Ts[e * 72 + m];
        }
    }
}

// ---------- Kernel 2: fused proj_c + bilinear attention ----------------------
// LDS (shorts): [0,8192) buf0 | Ws lo   [8192,16384) buf1 | Ws hi
//               [16384,24576) Ucs (phase-1) | Ps[16384,20992) (main loop)
// Total 49152 B -> LDS allows 3 blocks/CU.
// __launch_bounds__(256,2): round-4's (256,3) split the unified reg file at
// accum_offset~84 -> arch-VGPR starvation -> 59 MB scratch spill, 78 us.
// (256,2) measured 128 VGPR + no spill (round 2); ~160 total regs/wave still
// admits 3 waves/SIMD, so 3 blocks/CU is reachable WITHOUT the hard cap.
// Phase 1: Wu bf16 pre-swizzled+pre-scaled by log2(e), DMA'd to LDS; Uc stored
// swizzled in Ucs; all 64 Uc rows hoisted to Bg regs; ucred (scaled) in regs.
// Main loop per mt (2 VpT buffers, DMA issued at iteration TOP = ~full iter of
// latency cover): DMA(mt+1)->buf[(mt+1)&1]; A-prefetch(mt+1)->regs; QK from
// regs; exp2 -> Ps; barrier1 lgkm-only (DMA crosses); PV from buf[mt&1];
// barrier2 vmcnt(4) (drains DMA(mt+1), keeps 4 A-prefetches in flight; the
// sched_barrier after the DMA cluster pins DMA-older-than-Apf issue order).
static __device__ __forceinline__ void bar_lgkm() {
    asm volatile("s_waitcnt lgkmcnt(0)" ::: "memory");
    __builtin_amdgcn_s_barrier();
    __builtin_amdgcn_sched_barrier(0);
}

static __device__ __forceinline__ void attn_iter(
    int mt, unsigned short* smem, unsigned short* Ps,
    const unsigned short* __restrict__ vpb,
    const unsigned short* __restrict__ vtb,
    int wave, int lane, int n16, int q, int a_off,
    const bf16x8 (&Bg)[4][4],
    bf16x8 (&aC)[4], bf16x8 (&aN)[4],
    f32x4 (&O)[8], float (&lpart)[4])
{
    const int nx = (mt + 1 > 15) ? 15 : mt + 1;   // clamp keeps vmcnt uniform
    // DMA VpT tile mt+1 into buf[(mt+1)&1] (read next iteration)
    {
        const unsigned short* st = vtb + nx * 8192;
        unsigned short* dst = smem + ((mt + 1) & 1) * 8192 + wave * 2048;
        #pragma unroll
        for (int i = 0; i < 4; ++i) {
            int L = wave * 256 + i * 64 + lane;
            int r = L >> 3, sc = L & 7, c = sc ^ (r & 7);
            async16(st + r * 64 + c * 8, dst + i * 512);
        }
    }
    __builtin_amdgcn_sched_barrier(0);   // DMA issues before Apf (vmcnt order)
    // A-frag prefetch for tile mt+1 (global->reg, consumed next iteration)
    {
        const unsigned short* pa = vpb + nx * 8192 + a_off;
        #pragma unroll
        for (int kk = 0; kk < 4; ++kk)
            aN[kk] = *(const bf16x8*)(pa + kk * 32);
    }

    // QK (m-split): S^T rows m = wave*16+q*4+r, cols n = j*16+n16. Pure regs.
    f32x4 S[4];
    #pragma unroll
    for (int j = 0; j < 4; ++j) S[j] = {0.f, 0.f, 0.f, 0.f};
    __builtin_amdgcn_s_setprio(1);
    #pragma unroll
    for (int kk = 0; kk < 4; ++kk) {
        #pragma unroll
        for (int j = 0; j < 4; ++j)
            S[j] = __builtin_amdgcn_mfma_f32_16x16x32_bf16(aC[kk], Bg[j][kk], S[j], 0, 0, 0);
    }
    __builtin_amdgcn_s_setprio(0);

    // p = exp2(S) (Uc pre-scaled); write P[n][m] slices to shared Ps
    #pragma unroll
    for (int j = 0; j < 4; ++j) {
        float p0 = __builtin_exp2f(S[j][0]);
        float p1 = __builtin_exp2f(S[j][1]);
        float p2 = __builtin_exp2f(S[j][2]);
        float p3 = __builtin_exp2f(S[j][3]);
        lpart[j] += (p0 + p1) + (p2 + p3);
        uint2 u = { f2bf2(p0, p1), f2bf2(p2, p3) };
        *(uint2*)&Ps[(j * 16 + n16) * 72 + wave * 16 + q * 4] = u;
    }
    bar_lgkm();   // barrier 1: P complete; DMA + prefetch stay in flight

    // PV (n-split): O[n][d] for this wave's 16 n-rows; VTs = buf[mt&1]
    const unsigned short* VTs = smem + (mt & 1) * 8192;
    __builtin_amdgcn_s_setprio(1);
    #pragma unroll
    for (int kk = 0; kk < 2; ++kk) {
        bf16x8 a = *(const bf16x8*)&Ps[(wave * 16 + n16) * 72 + kk * 32 + q * 8];
        #pragma unroll
        for (int j = 0; j < 8; ++j) {
            bf16x8 bb = *(const bf16x8*)&VTs[(j * 16 + n16) * 64 + ((kk * 4 + q) ^ (n16 & 7)) * 8];
            O[j] = __builtin_amdgcn_mfma_f32_16x16x32_bf16(a, bb, O[j], 0, 0, 0);
        }
    }
    __builtin_amdgcn_s_setprio(0);
    // barrier 2: Ps/VTs reads done; DMA(mt+1) drained; Apf(mt+1) in flight
    asm volatile("s_waitcnt vmcnt(4) lgkmcnt(0)" ::: "memory");
    __builtin_amdgcn_s_barrier();
    __builtin_amdgcn_sched_barrier(0);
}

__global__ __launch_bounds__(256, 2) void attn_kernel(
    const float* __restrict__ hc,             // (B*512,128) fp32
    const unsigned short* __restrict__ Wub,   // (128,128) bf16 swz, pre-scaled
    const float* __restrict__ Ub,             // (128) fp32
    const unsigned short* __restrict__ Vp,    // (B,16,64,128) bf16 tiled
    const unsigned short* __restrict__ VpT,   // (B,16,128,64) bf16 tiled
    float* __restrict__ part)                 // (B*8,128) fp32
{
    __shared__ __align__(16) unsigned short smem[24576];   // 49152 B
    unsigned short* Ws  = smem;            // phase-1: 16384 shorts
    unsigned short* Ucs = smem + 16384;    // phase-1: 8192 shorts (swizzled)
    unsigned short* Ps  = smem + 16384;    // main loop: 4608 shorts

    const int t = threadIdx.x;
    const int lane = t & 63;
    const int wave = t >> 6;
    const int n16 = lane & 15, q = lane >> 4;

    const int id = blockIdx.x;
    const int xcd = id & 7;
    const int slot = id >> 3;
    const int b = xcd * 8 + (slot >> 3);
    const int nt = slot & 7;

    const unsigned short* vpb = Vp + (long)b * MM * DD;    // 16 tiles of 8192
    const unsigned short* vtb = VpT + (long)b * MM * DD;

    const float LOG2E = 1.44269504088896f;
    const float RLN2  = 0.69314718055994531f;   // 1/log2(e)

    // ---- Phase 1: Uc (pre-scaled by log2e via W) for this block's 64 rows ----
    float4 xv[8];
    {
        const float* xrow = hc + ((long)b * NN + nt * 64 + wave * 16 + n16) * DD + q * 8;
        #pragma unroll
        for (int kk = 0; kk < 4; ++kk) {
            xv[2 * kk]     = *(const float4*)(xrow + kk * 32);
            xv[2 * kk + 1] = *(const float4*)(xrow + kk * 32 + 4);
        }
    }
    #pragma unroll
    for (int i = 0; i < 8; ++i)
        async16(Wub + (wave * 512 + i * 64 + lane) * 8, Ws + wave * 4096 + i * 512);
    __syncthreads();

    f32x4 acc[8];
    #pragma unroll
    for (int j = 0; j < 8; ++j) acc[j] = {0.f, 0.f, 0.f, 0.f};
    #pragma unroll
    for (int kk = 0; kk < 4; ++kk) {
        float4 x0 = xv[2 * kk], x1 = xv[2 * kk + 1];
        union { bf16x8 v; unsigned int u[4]; } a;
        a.u[0] = f2bf2(x0.x, x0.y); a.u[1] = f2bf2(x0.z, x0.w);
        a.u[2] = f2bf2(x1.x, x1.y); a.u[3] = f2bf2(x1.z, x1.w);
        #pragma unroll
        for (int j = 0; j < 8; ++j) {
            bf16x8 bb = *(const bf16x8*)&Ws[(j * 16 + n16) * 128
                                            + (((q + 4 * kk) ^ (n16 & 7)) << 3)];
            acc[j] = __builtin_amdgcn_mfma_f32_16x16x32_bf16(a.v, bb, acc[j], 0, 0, 0);
        }
    }
    float ucred[8];
    #pragma unroll
    for (int j = 0; j < 8; ++j) {
        const float bv = Ub[j * 16 + n16] * LOG2E;   // match pre-scaled W
        float s = 0.f;
        #pragma unroll
        for (int r = 0; r < 4; ++r) {
            float v = acc[j][r] + bv;
            v = v > 0.f ? v : 0.f;
            s += v;                                   // scaled; x RLN2 at end
            int row = wave * 16 + q * 4 + r;
            int pc = (2 * j + (n16 >> 3)) ^ (row & 7);
            Ucs[row * 128 + pc * 8 + (n16 & 7)] = f2bf(v);
        }
        ucred[j] = s;
    }
    __syncthreads();                          // (A): Ucs ready, Ws dead

    // ALL 64 n-rows of Uc as B-frags in registers (16 frags = 64 VGPRs)
    bf16x8 Bg[4][4];
    #pragma unroll
    for (int j = 0; j < 4; ++j)
        #pragma unroll
        for (int kk = 0; kk < 4; ++kk)
            Bg[j][kk] = *(const bf16x8*)&Ucs[(j * 16 + n16) * 128
                                             + (((q + 4 * kk) ^ (n16 & 7)) << 3)];

    // Prologue: A-frags tile 0 + DMA VpT tile 0 into buf0 (Ws dead)
    const int a_off = (wave * 16 + n16) * 128 + q * 8;
    bf16x8 aA[4], aB[4];
    #pragma unroll
    for (int kk = 0; kk < 4; ++kk)
        aA[kk] = *(const bf16x8*)&vpb[a_off + kk * 32];
    {
        unsigned short* dst = smem + wave * 2048;
        #pragma unroll
        for (int i = 0; i < 4; ++i) {
            int L = wave * 256 + i * 64 + lane;
            int r = L >> 3, sc = L & 7, c = sc ^ (r & 7);
            async16(vtb + r * 64 + c * 8, dst + i * 512);
        }
    }
    asm volatile("s_waitcnt vmcnt(0) lgkmcnt(0)" ::: "memory");
    __builtin_amdgcn_s_barrier();
    __builtin_amdgcn_sched_barrier(0);

    // ---- Main loop ----
    f32x4 O[8];
    #pragma unroll
    for (int j = 0; j < 8; ++j) O[j] = {0.f, 0.f, 0.f, 0.f};
    float lpart[4] = {0.f, 0.f, 0.f, 0.f};

    #pragma unroll 1
    for (int mt = 0; mt < 16; mt += 2) {
        attn_iter(mt,     smem, Ps, vpb, vtb, wave, lane, n16, q, a_off, Bg, aA, aB, O, lpart);
        attn_iter(mt + 1, smem, Ps, vpb, vtb, wave, lane, n16, q, a_off, Bg, aB, aA, O, lpart);
    }

    // ---- l reduction: lpart[j] covers n = j*16+n16 over this wave's m & q ----
    #pragma unroll
    for (int j = 0; j < 4; ++j) {
        lpart[j] += __shfl_xor(lpart[j], 16);
        lpart[j] += __shfl_xor(lpart[j], 32);
    }
    float* lred = (float*)Ps;               // 256 floats
    float* red  = (float*)Ps + 256;         // 512 floats
    if (q == 0) {
        #pragma unroll
        for (int j = 0; j < 4; ++j)
            lred[wave * 64 + j * 16 + n16] = lpart[j];
    }
    __syncthreads();

    float inv[4];
    #pragma unroll
    for (int r = 0; r < 4; ++r) {
        int n = wave * 16 + q * 4 + r;
        inv[r] = 1.0f / (lred[n] + lred[64 + n] + lred[128 + n] + lred[192 + n]);
    }

    // per-wave partial over its 16 n-rows, then cross-wave reduction
    #pragma unroll
    for (int j = 0; j < 8; ++j) {
        float s = ucred[j] * RLN2
                + O[j][0] * inv[0] + O[j][1] * inv[1]
                + O[j][2] * inv[2] + O[j][3] * inv[3];
        s += __shfl_xor(s, 16);
        s += __shfl_xor(s, 32);
        if (q == 0)
            red[wave * 128 + j * 16 + n16] = s;
    }
    __syncthreads();
    if (t < 128) {
        float tot = red[t] + red[128 + t] + red[256 + t] + red[384 + t];
        part[(long)(b * 8 + nt) * DD + t] = tot;
    }
}

// ---------- Kernel 3: out[b][d] = (Sigma_nt part) * q[d] / N -----------------
__global__ __launch_bounds__(256) void finalize_kernel(
    const float* __restrict__ part, const float* __restrict__ qv,
    float* __restrict__ out)
{
    int i = blockIdx.x * 256 + threadIdx.x;     // 8192
    int b = i >> 7, d = i & 127;
    const float* p = part + (long)b * 8 * DD + d;
    float s = 0.f;
    #pragma unroll
    for (int nt = 0; nt < 8; ++nt) s += p[nt * DD];
    out[i] = s * qv[d] * (1.0f / (float)NN);
}

extern "C" void kernel_launch(void* const* d_in, const int* in_sizes, int n_in,
                              void* d_out, int out_size, void* d_ws, size_t ws_size,
                              hipStream_t stream) {
    const float* h_c = (const float*)d_in[0];
    const float* h_p = (const float*)d_in[1];
    const float* U_w = (const float*)d_in[2];
    const float* U_b = (const float*)d_in[3];
    const float* V_w = (const float*)d_in[4];
    const float* V_b = (const float*)d_in[5];
    const float* qv  = (const float*)d_in[6];
    float* out = (float*)d_out;

    unsigned short* Vp  = (unsigned short*)d_ws;                 // (B,16,64,128) bf16
    unsigned short* VpT = Vp + (size_t)BB * MM * DD;             // (B,16,128,64) bf16
    float* part = (float*)(VpT + (size_t)BB * MM * DD);          // (B*8,128) fp32
    unsigned short* Wcv = (unsigned short*)(part + (size_t)BB * 8 * DD); // 2x 16384

    wcvt_kernel<<<2, 256, 0, stream>>>(U_w, V_w, Wcv);
    proj_v_kernel<<<BB * MM / 64, 256, 0, stream>>>(h_p, Wcv + 16384, V_b, Vp, VpT);
    attn_kernel<<<512, 256, 0, stream>>>(h_c, Wcv, U_b, Vp, VpT, part);
    finalize_kernel<<<32, 256, 0, stream>>>(part, qv, out);
}